// Round 13
// baseline (395.340 us; speedup 1.0000x reference)
//
#include <hip/hip_runtime.h>
#include <math.h>

#define HD   48
#define WD   48
#define BB   8
#define DM   96
#define DIN  192
#define LL   2304   // HD*WD
#define NN   16
#define RR   6
#define KK   4
#define CH   32     // scan chunk length
#define NC   72     // LL / CH

#define LOG2E 1.44269504f
#define LN2   0.69314718f

// ---------------------------------------------------------------------------
// K1: in_proj GEMM  (M=B*L=18432, K=96, N=384) + split + silu(z)
// ---------------------------------------------------------------------------
__global__ __launch_bounds__(256) void k_inproj(const float* __restrict__ x,
                                                const float* __restrict__ w,
                                                float* __restrict__ xc,
                                                float* __restrict__ zb) {
    __shared__ float sa[64 * 97];
    __shared__ float sb[96 * 68];
    const int tid = threadIdx.x;
    const int p0 = blockIdx.x * 64;
    const int n0 = blockIdx.y * 64;

    for (int i = tid; i < 64 * 96; i += 256) {
        int r = i / 96, c = i % 96;
        sa[r * 97 + c] = x[(size_t)(p0 + r) * 96 + c];
    }
    for (int i = tid; i < 64 * 96; i += 256) {
        int n = i / 96, c = i % 96;
        sb[c * 68 + n] = w[(size_t)(n0 + n) * 96 + c];
    }
    __syncthreads();

    const int tx = tid & 15, ty = tid >> 4;
    const int r0 = ty * 4, c0 = tx * 4;
    float acc[4][4] = {};
    for (int k = 0; k < 96; ++k) {
        float a0 = sa[(r0 + 0) * 97 + k];
        float a1 = sa[(r0 + 1) * 97 + k];
        float a2 = sa[(r0 + 2) * 97 + k];
        float a3 = sa[(r0 + 3) * 97 + k];
        float4 bv = *(const float4*)&sb[k * 68 + c0];
        acc[0][0] += a0 * bv.x; acc[0][1] += a0 * bv.y; acc[0][2] += a0 * bv.z; acc[0][3] += a0 * bv.w;
        acc[1][0] += a1 * bv.x; acc[1][1] += a1 * bv.y; acc[1][2] += a1 * bv.z; acc[1][3] += a1 * bv.w;
        acc[2][0] += a2 * bv.x; acc[2][1] += a2 * bv.y; acc[2][2] += a2 * bv.z; acc[2][3] += a2 * bv.w;
        acc[3][0] += a3 * bv.x; acc[3][1] += a3 * bv.y; acc[3][2] += a3 * bv.z; acc[3][3] += a3 * bv.w;
    }
    for (int i = 0; i < 4; ++i) {
        int p = p0 + r0 + i;
        for (int j = 0; j < 4; ++j) {
            int n = n0 + c0 + j;
            float v = acc[i][j];
            if (n < DIN) {
                xc[(size_t)p * DIN + n] = v;
            } else {
                float s = v / (1.f + __expf(-v));
                zb[(size_t)p * DIN + (n - DIN)] = s;
            }
        }
    }
}

// ---------------------------------------------------------------------------
// K2: depthwise 3x3 conv + bias + silu (channel-last); row- and col-major out
// ---------------------------------------------------------------------------
__global__ __launch_bounds__(192) void k_conv(const float* __restrict__ xc,
                                              const float* __restrict__ cw,
                                              const float* __restrict__ cb,
                                              float* __restrict__ xs0,
                                              float* __restrict__ xs1) {
    const int p = blockIdx.x;
    const int d = threadIdx.x;
    const int b = p / LL;
    const int hw = p % LL;
    const int h = hw / WD, w = hw % WD;

    float acc = cb[d];
    #pragma unroll
    for (int ky = 0; ky < 3; ++ky) {
        int hy = h + ky - 1;
        if ((unsigned)hy >= HD) continue;
        #pragma unroll
        for (int kx = 0; kx < 3; ++kx) {
            int wx = w + kx - 1;
            if ((unsigned)wx >= WD) continue;
            acc += xc[((size_t)(b * HD + hy) * WD + wx) * DIN + d] * cw[d * 9 + ky * 3 + kx];
        }
    }
    float v = acc / (1.f + __expf(-acc));
    xs0[((size_t)b * LL + h * WD + w) * DIN + d] = v;
    xs1[((size_t)b * LL + w * HD + h) * DIN + d] = v;
}

// ---------------------------------------------------------------------------
// K3: x_proj, all 4 directions from ONE pixel staging. LDS = pixel tile only
// (25 KB -> ~6 blocks/CU); weights read direct from global (L1/L2-resident,
// half-wave-uniform -> broadcast). One __syncthreads total.
// ---------------------------------------------------------------------------
__global__ __launch_bounds__(256) void k_xproj(const float* __restrict__ xs0,
                                               const float* __restrict__ wxp,
                                               float* __restrict__ dtr,
                                               float* __restrict__ Bt,
                                               float* __restrict__ Ct) {
    __shared__ float sxs[32 * 196];
    const int b = blockIdx.y;
    const int tid = threadIdx.x;
    const int t0 = blockIdx.x * 32;

    for (int i = tid; i < 32 * 48; i += 256) {
        int r = i / 48, j = i % 48;
        ((float4*)&sxs[r * 196])[j] =
            ((const float4*)&xs0[((size_t)b * LL + t0 + r) * DIN])[j];
    }
    __syncthreads();

    const int lp = tid & 31;
    const int c0 = (tid >> 5) * 5;    // 0,5,...,35 (rows 38,39 of group 7 invalid)
    const int t = t0 + lp;
    const int hh = t / WD, ww = t % WD;
    const int t1 = ww * HD + hh;
    const float* x0 = &sxs[lp * 196];

    for (int k = 0; k < KK; ++k) {
        const float* wb = &wxp[(size_t)k * 38 * 192];
        const float* w0 = wb + (size_t)(c0 + 0) * 192;
        const float* w1 = wb + (size_t)(c0 + 1) * 192;
        const float* w2 = wb + (size_t)(c0 + 2) * 192;
        const float* w3 = (c0 + 3 < 38) ? wb + (size_t)(c0 + 3) * 192 : wb;
        const float* w4 = (c0 + 4 < 38) ? wb + (size_t)(c0 + 4) * 192 : wb;
        float acc0 = 0.f, acc1 = 0.f, acc2 = 0.f, acc3 = 0.f, acc4 = 0.f;
        #pragma unroll 4
        for (int d = 0; d < 192; d += 4) {
            float4 a  = *(const float4*)&x0[d];
            float4 v0 = *(const float4*)&w0[d];
            float4 v1 = *(const float4*)&w1[d];
            float4 v2 = *(const float4*)&w2[d];
            float4 v3 = *(const float4*)&w3[d];
            float4 v4 = *(const float4*)&w4[d];
            acc0 += a.x * v0.x + a.y * v0.y + a.z * v0.z + a.w * v0.w;
            acc1 += a.x * v1.x + a.y * v1.y + a.z * v1.z + a.w * v1.w;
            acc2 += a.x * v2.x + a.y * v2.y + a.z * v2.z + a.w * v2.w;
            acc3 += a.x * v3.x + a.y * v3.y + a.z * v3.z + a.w * v3.w;
            acc4 += a.x * v4.x + a.y * v4.y + a.z * v4.z + a.w * v4.w;
        }

        int tk;
        if (k == 0)      tk = t;
        else if (k == 1) tk = t1;
        else if (k == 2) tk = LL - 1 - t;
        else             tk = LL - 1 - t1;
        size_t base = (size_t)(b * KK + k) * LL + tk;
        float accs[5] = {acc0, acc1, acc2, acc3, acc4};
        #pragma unroll
        for (int j = 0; j < 5; ++j) {
            int c = c0 + j;
            if (c < RR)               dtr[base * RR + c] = accs[j];
            else if (c < RR + NN)     Bt[base * NN + (c - RR)] = accs[j];
            else if (c < RR + 2 * NN) Ct[base * NN + (c - RR - NN)] = accs[j];
        }
    }
}

// ---------------------------------------------------------------------------
// K4a: THE scan (single sequential pass). Chunk-local h (h0=0); emits
// y_loc + Ds*u via atomicAdd into merged yacc; stores hend + ssp.
// ---------------------------------------------------------------------------
__global__ __launch_bounds__(192) void k_scan(const float* __restrict__ xs0,
                                              const float* __restrict__ xs1,
                                              const float* __restrict__ dtr,
                                              const float* __restrict__ Bt,
                                              const float* __restrict__ Ct,
                                              const float* __restrict__ A_logs,
                                              const float* __restrict__ Ds,
                                              const float* __restrict__ dtw,
                                              const float* __restrict__ dtb,
                                              float* __restrict__ hend,
                                              float* __restrict__ ssp,
                                              float* __restrict__ yacc) {
    __shared__ __align__(16) float sB[CH * NN];
    __shared__ __align__(16) float sC[CH * NN];
    __shared__ __align__(16) float sdt[CH * RR];
    const int c = blockIdx.x, k = blockIdx.y, b = blockIdx.z;
    const int d = threadIdx.x;
    const int kd = k * DIN + d;
    const size_t baseBK = (size_t)(b * KK + k) * LL;
    const int t0 = c * CH;

    for (int i = threadIdx.x; i < CH * NN; i += 192) {
        sB[i] = Bt[(baseBK + t0) * NN + i];
        sC[i] = Ct[(baseBK + t0) * NN + i];
    }
    for (int i = threadIdx.x; i < CH * RR; i += 192) sdt[i] = dtr[(baseBK + t0) * RR + i];
    __syncthreads();

    float a2_[NN];
    #pragma unroll
    for (int n = 0; n < NN; ++n) a2_[n] = -__expf(A_logs[(size_t)kd * NN + n]) * LOG2E;
    float w_[RR];
    #pragma unroll
    for (int r = 0; r < RR; ++r) w_[r] = dtw[(size_t)kd * RR + r];
    const float bias = dtb[kd];
    const float Dv = Ds[kd];
    float h[NN];
    #pragma unroll
    for (int n = 0; n < NN; ++n) h[n] = 0.f;
    float sum_sp = 0.f;

    const float* u_src = (k & 1) ? xs1 : xs0;
    float u_next = u_src[((size_t)b * LL + ((k < 2) ? t0 : (LL - 1 - t0))) * DIN + d];

    for (int tt = 0; tt < CH; ++tt) {
        float u = u_next;
        if (tt + 1 < CH) {
            int tn = t0 + tt + 1;
            int ts = (k < 2) ? tn : (LL - 1 - tn);
            u_next = u_src[((size_t)b * LL + ts) * DIN + d];
        }
        const float2* dr = (const float2*)&sdt[tt * RR];
        float2 d0 = dr[0], d1 = dr[1], d2 = dr[2];
        float xv = bias + d0.x * w_[0] + d0.y * w_[1] + d1.x * w_[2]
                        + d1.y * w_[3] + d2.x * w_[4] + d2.y * w_[5];
        float sp = (xv > 15.f) ? xv
                 : __builtin_amdgcn_logf(1.f + __builtin_amdgcn_exp2f(xv * LOG2E)) * LN2;
        sum_sp += sp;
        float du = sp * u;
        const float4* Bp = (const float4*)&sB[tt * NN];
        const float4* Cp = (const float4*)&sC[tt * NN];
        float y = 0.f;
        #pragma unroll
        for (int q = 0; q < 4; ++q) {
            float4 Bv = Bp[q], Cv = Cp[q];
            h[4*q+0] = __builtin_amdgcn_exp2f(sp * a2_[4*q+0]) * h[4*q+0] + du * Bv.x; y += h[4*q+0] * Cv.x;
            h[4*q+1] = __builtin_amdgcn_exp2f(sp * a2_[4*q+1]) * h[4*q+1] + du * Bv.y; y += h[4*q+1] * Cv.y;
            h[4*q+2] = __builtin_amdgcn_exp2f(sp * a2_[4*q+2]) * h[4*q+2] + du * Bv.z; y += h[4*q+2] * Cv.z;
            h[4*q+3] = __builtin_amdgcn_exp2f(sp * a2_[4*q+3]) * h[4*q+3] + du * Bv.w; y += h[4*q+3] * Cv.w;
        }
        y += Dv * u;

        int t = t0 + tt;
        int pos;
        if (k == 0)      pos = t;
        else if (k == 2) pos = LL - 1 - t;
        else if (k == 1) pos = (t % HD) * WD + (t / HD);
        else { int tr = LL - 1 - t; pos = (tr % HD) * WD + (tr / HD); }

        atomicAdd(&yacc[((size_t)b * LL + pos) * DIN + d], y);
    }

    size_t ob = (((size_t)(b * KK + k) * NC + c) * DIN + d) * NN;
    #pragma unroll
    for (int q = 0; q < 4; ++q) {
        *(float4*)&hend[ob + 4 * q] = make_float4(h[4*q], h[4*q+1], h[4*q+2], h[4*q+3]);
    }
    ssp[((size_t)c * (BB * KK) + (b * KK + k)) * DIN + d] = sum_sp;
}

// ---------------------------------------------------------------------------
// K4b: combine chunk states (in place: hend[c] <- h_start for chunk c)
// ---------------------------------------------------------------------------
__global__ __launch_bounds__(256) void k_comb(float* __restrict__ hend,
                                              const float* __restrict__ ssp,
                                              const float* __restrict__ A_logs) {
    const int gid = blockIdx.x * 256 + threadIdx.x;   // ((bk*DIN)+d)*16 + n
    const int n = gid & 15;
    const int dkb = gid >> 4;
    const int d = dkb % DIN;
    const int bk = dkb / DIN;
    const int k = bk & 3;
    const float a2 = -__expf(A_logs[(size_t)(k * DIN + d) * NN + n]) * LOG2E;
    float h = 0.f;
    for (int c = 0; c < NC; ++c) {
        size_t idx = (((size_t)bk * NC + c) * DIN + d) * NN + n;
        float e = hend[idx];
        hend[idx] = h;
        float P = __builtin_amdgcn_exp2f(a2 * ssp[((size_t)c * (BB * KK) + bk) * DIN + d]);
        h = P * h + e;
    }
}

// ---------------------------------------------------------------------------
// K4c: parallel correction: yacc[pos] += C_t . (exp2(a2*S_t) * h0).
// No recurrence; chunk 0 skipped (h0=0).
// ---------------------------------------------------------------------------
__global__ __launch_bounds__(192) void k_corr(const float* __restrict__ dtr,
                                              const float* __restrict__ Ct,
                                              const float* __restrict__ A_logs,
                                              const float* __restrict__ dtw,
                                              const float* __restrict__ dtb,
                                              const float* __restrict__ hstart,
                                              float* __restrict__ yacc) {
    if (blockIdx.x == 0) return;
    __shared__ __align__(16) float sC[CH * NN];
    __shared__ __align__(16) float sdt[CH * RR];
    const int c = blockIdx.x, k = blockIdx.y, b = blockIdx.z;
    const int d = threadIdx.x;
    const int kd = k * DIN + d;
    const size_t baseBK = (size_t)(b * KK + k) * LL;
    const int t0 = c * CH;

    for (int i = threadIdx.x; i < CH * NN; i += 192) sC[i] = Ct[(baseBK + t0) * NN + i];
    for (int i = threadIdx.x; i < CH * RR; i += 192) sdt[i] = dtr[(baseBK + t0) * RR + i];
    __syncthreads();

    float a2_[NN];
    #pragma unroll
    for (int n = 0; n < NN; ++n) a2_[n] = -__expf(A_logs[(size_t)kd * NN + n]) * LOG2E;
    float w_[RR];
    #pragma unroll
    for (int r = 0; r < RR; ++r) w_[r] = dtw[(size_t)kd * RR + r];
    const float bias = dtb[kd];

    float h0[NN];
    size_t hb = (((size_t)(b * KK + k) * NC + c) * DIN + d) * NN;
    #pragma unroll
    for (int q = 0; q < 4; ++q) {
        float4 hv = *(const float4*)&hstart[hb + 4 * q];
        h0[4*q] = hv.x; h0[4*q+1] = hv.y; h0[4*q+2] = hv.z; h0[4*q+3] = hv.w;
    }

    float ssum = 0.f;
    for (int tt = 0; tt < CH; ++tt) {
        const float2* dr = (const float2*)&sdt[tt * RR];
        float2 d0 = dr[0], d1 = dr[1], d2 = dr[2];
        float xv = bias + d0.x * w_[0] + d0.y * w_[1] + d1.x * w_[2]
                        + d1.y * w_[3] + d2.x * w_[4] + d2.y * w_[5];
        float sp = (xv > 15.f) ? xv
                 : __builtin_amdgcn_logf(1.f + __builtin_amdgcn_exp2f(xv * LOG2E)) * LN2;
        ssum += sp;
        const float4* Cp = (const float4*)&sC[tt * NN];
        float acc = 0.f;
        #pragma unroll
        for (int q = 0; q < 4; ++q) {
            float4 Cv = Cp[q];
            acc += Cv.x * (__builtin_amdgcn_exp2f(ssum * a2_[4*q+0]) * h0[4*q+0]);
            acc += Cv.y * (__builtin_amdgcn_exp2f(ssum * a2_[4*q+1]) * h0[4*q+1]);
            acc += Cv.z * (__builtin_amdgcn_exp2f(ssum * a2_[4*q+2]) * h0[4*q+2]);
            acc += Cv.w * (__builtin_amdgcn_exp2f(ssum * a2_[4*q+3]) * h0[4*q+3]);
        }

        int t = t0 + tt;
        int pos;
        if (k == 0)      pos = t;
        else if (k == 2) pos = LL - 1 - t;
        else if (k == 1) pos = (t % HD) * WD + (t / HD);
        else { int tr = LL - 1 - t; pos = (tr % HD) * WD + (tr / HD); }

        atomicAdd(&yacc[((size_t)b * LL + pos) * DIN + d], acc);
    }
}

// ---------------------------------------------------------------------------
// K5: fused LayerNorm + gate + out_proj as LDS-tiled GEMM (reads merged yacc).
// ---------------------------------------------------------------------------
__global__ __launch_bounds__(256) void k_final(const float* __restrict__ yacc,
                                               const float* __restrict__ zb,
                                               const float* __restrict__ g,
                                               const float* __restrict__ bta,
                                               const float* __restrict__ wo,
                                               float* __restrict__ out) {
    __shared__ float syn[32 * 194];
    __shared__ float swo[96 * 98];
    const int tid = threadIdx.x;
    const int P0 = blockIdx.x * 32;

    {
        const int p = tid >> 3;
        const int q = tid & 7;
        const float* yr = &yacc[((size_t)(P0 + p)) * DIN + q * 24];
        float4 v0 = ((const float4*)yr)[0];
        float4 v1 = ((const float4*)yr)[1];
        float4 v2 = ((const float4*)yr)[2];
        float4 v3 = ((const float4*)yr)[3];
        float4 v4 = ((const float4*)yr)[4];
        float4 v5 = ((const float4*)yr)[5];
        float s  = v0.x+v0.y+v0.z+v0.w + v1.x+v1.y+v1.z+v1.w + v2.x+v2.y+v2.z+v2.w
                 + v3.x+v3.y+v3.z+v3.w + v4.x+v4.y+v4.z+v4.w + v5.x+v5.y+v5.z+v5.w;
        float sq = v0.x*v0.x+v0.y*v0.y+v0.z*v0.z+v0.w*v0.w
                 + v1.x*v1.x+v1.y*v1.y+v1.z*v1.z+v1.w*v1.w
                 + v2.x*v2.x+v2.y*v2.y+v2.z*v2.z+v2.w*v2.w
                 + v3.x*v3.x+v3.y*v3.y+v3.z*v3.z+v3.w*v3.w
                 + v4.x*v4.x+v4.y*v4.y+v4.z*v4.z+v4.w*v4.w
                 + v5.x*v5.x+v5.y*v5.y+v5.z*v5.z+v5.w*v5.w;
        #pragma unroll
        for (int off = 1; off < 8; off <<= 1) {
            s  += __shfl_xor(s, off);
            sq += __shfl_xor(sq, off);
        }
        float mu = s * (1.f / DIN);
        float rs = rsqrtf(sq * (1.f / DIN) - mu * mu + 1e-5f);

        const float* zr = &zb[((size_t)(P0 + p)) * DIN + q * 24];
        const float* gr = &g[q * 24];
        const float* br = &bta[q * 24];
        float* sy = &syn[p * 194 + q * 24];
        #pragma unroll
        for (int j = 0; j < 6; ++j) {
            float4 vv = (j == 0) ? v0 : (j == 1) ? v1 : (j == 2) ? v2
                      : (j == 3) ? v3 : (j == 4) ? v4 : v5;
            float4 gv = ((const float4*)gr)[j];
            float4 bv = ((const float4*)br)[j];
            float4 zv = ((const float4*)zr)[j];
            float t0 = ((vv.x - mu) * rs * gv.x + bv.x) * zv.x;
            float t1 = ((vv.y - mu) * rs * gv.y + bv.y) * zv.y;
            float t2 = ((vv.z - mu) * rs * gv.z + bv.z) * zv.z;
            float t3 = ((vv.w - mu) * rs * gv.w + bv.w) * zv.w;
            ((float2*)sy)[2 * j]     = make_float2(t0, t1);
            ((float2*)sy)[2 * j + 1] = make_float2(t2, t3);
        }
    }

    const int tx = tid & 15;
    const int ty = tid >> 4;
    const int c0 = tx * 6;
    const int p0 = ty * 2;
    float acc[2][6] = {};

    for (int kb = 0; kb < 2; ++kb) {
        __syncthreads();
        for (int i = tid; i < 96 * 96; i += 256) {
            int n = i / 96, k = i - n * 96;
            swo[k * 98 + n] = wo[(size_t)n * DIN + kb * 96 + k];
        }
        __syncthreads();
        const float* sy0 = &syn[p0 * 194 + kb * 96];
        const float* sy1 = &syn[(p0 + 1) * 194 + kb * 96];
        #pragma unroll 4
        for (int k = 0; k < 96; ++k) {
            float a0 = sy0[k];
            float a1 = sy1[k];
            const float2* wp = (const float2*)&swo[k * 98 + c0];
            float2 w01 = wp[0], w23 = wp[1], w45 = wp[2];
            acc[0][0] += a0 * w01.x; acc[0][1] += a0 * w01.y;
            acc[0][2] += a0 * w23.x; acc[0][3] += a0 * w23.y;
            acc[0][4] += a0 * w45.x; acc[0][5] += a0 * w45.y;
            acc[1][0] += a1 * w01.x; acc[1][1] += a1 * w01.y;
            acc[1][2] += a1 * w23.x; acc[1][3] += a1 * w23.y;
            acc[1][4] += a1 * w45.x; acc[1][5] += a1 * w45.y;
        }
    }

    #pragma unroll
    for (int i = 0; i < 2; ++i) {
        float* orow = &out[((size_t)(P0 + p0 + i)) * DM + c0];
        orow[0] = acc[i][0]; orow[1] = acc[i][1]; orow[2] = acc[i][2];
        orow[3] = acc[i][3]; orow[4] = acc[i][4]; orow[5] = acc[i][5];
    }
}

// ---------------------------------------------------------------------------
extern "C" void kernel_launch(void* const* d_in, const int* in_sizes, int n_in,
                              void* d_out, int out_size, void* d_ws, size_t ws_size,
                              hipStream_t stream) {
    const float* x      = (const float*)d_in[0];
    const float* w_in   = (const float*)d_in[1];
    const float* conv_w = (const float*)d_in[2];
    const float* conv_b = (const float*)d_in[3];
    const float* w_xp   = (const float*)d_in[4];
    const float* dtw    = (const float*)d_in[5];
    const float* dtb    = (const float*)d_in[6];
    const float* A_logs = (const float*)d_in[7];
    const float* Ds     = (const float*)d_in[8];
    const float* ln_g   = (const float*)d_in[9];
    const float* ln_b   = (const float*)d_in[10];
    const float* w_out  = (const float*)d_in[11];
    float* out = (float*)d_out;

    float* ws = (float*)d_ws;
    size_t o = 0;
    float* xc  = ws + o; o += (size_t)BB * LL * DIN;
    float* zb  = ws + o; o += (size_t)BB * LL * DIN;
    float* xs0 = ws + o; o += (size_t)BB * LL * DIN;
    float* xs1 = ws + o; o += (size_t)BB * LL * DIN;
    float* Btb = ws + o; o += (size_t)BB * KK * LL * NN;
    float* Ctb = ws + o; o += (size_t)BB * KK * LL * NN;
    float* dtrb= ws + o; o += (size_t)BB * KK * LL * RR;
    float* yac = ws + o; o += (size_t)BB * LL * DIN;
    float* hend= ws + o; o += (size_t)BB * KK * NC * DIN * NN;
    float* ssp = ws + o; o += (size_t)NC * BB * KK * DIN;

    hipMemsetAsync(yac, 0, sizeof(float) * (size_t)BB * LL * DIN, stream);

    dim3 g1(288, 6);
    k_inproj<<<g1, 256, 0, stream>>>(x, w_in, xc, zb);

    k_conv<<<BB * LL, DIN, 0, stream>>>(xc, conv_w, conv_b, xs0, xs1);

    dim3 g3(LL / 32, BB);
    k_xproj<<<g3, 256, 0, stream>>>(xs0, w_xp, dtrb, Btb, Ctb);

    dim3 gs(NC, KK, BB);
    k_scan<<<gs, DIN, 0, stream>>>(xs0, xs1, dtrb, Btb, Ctb, A_logs, Ds, dtw, dtb,
                                   hend, ssp, yac);
    k_comb<<<(BB * KK * DIN * NN) / 256, 256, 0, stream>>>(hend, ssp, A_logs);
    k_corr<<<gs, DIN, 0, stream>>>(dtrb, Ctb, A_logs, dtw, dtb, hend, yac);

    k_final<<<BB * LL / 32, 256, 0, stream>>>(yac, zb, ln_g, ln_b, w_out, out);
}

// Round 16
// 324.129 us; speedup vs baseline: 1.2197x; 1.2197x over previous
//
#include <hip/hip_runtime.h>
#include <math.h>

#define HD   48
#define WD   48
#define BB   8
#define DM   96
#define DIN  192
#define LL   2304   // HD*WD
#define NN   16
#define RR   6
#define KK   4
#define CH   32     // scan chunk length
#define NC   72     // LL / CH

#define LOG2E 1.44269504f
#define LN2   0.69314718f

// ---------------------------------------------------------------------------
// K1: in_proj GEMM  (M=B*L=18432, K=96, N=384) + split + silu(z)
// ---------------------------------------------------------------------------
__global__ __launch_bounds__(256) void k_inproj(const float* __restrict__ x,
                                                const float* __restrict__ w,
                                                float* __restrict__ xc,
                                                float* __restrict__ zb) {
    __shared__ float sa[64 * 97];
    __shared__ float sb[96 * 68];
    const int tid = threadIdx.x;
    const int p0 = blockIdx.x * 64;
    const int n0 = blockIdx.y * 64;

    for (int i = tid; i < 64 * 96; i += 256) {
        int r = i / 96, c = i % 96;
        sa[r * 97 + c] = x[(size_t)(p0 + r) * 96 + c];
    }
    for (int i = tid; i < 64 * 96; i += 256) {
        int n = i / 96, c = i % 96;
        sb[c * 68 + n] = w[(size_t)(n0 + n) * 96 + c];
    }
    __syncthreads();

    const int tx = tid & 15, ty = tid >> 4;
    const int r0 = ty * 4, c0 = tx * 4;
    float acc[4][4] = {};
    for (int k = 0; k < 96; ++k) {
        float a0 = sa[(r0 + 0) * 97 + k];
        float a1 = sa[(r0 + 1) * 97 + k];
        float a2 = sa[(r0 + 2) * 97 + k];
        float a3 = sa[(r0 + 3) * 97 + k];
        float4 bv = *(const float4*)&sb[k * 68 + c0];
        acc[0][0] += a0 * bv.x; acc[0][1] += a0 * bv.y; acc[0][2] += a0 * bv.z; acc[0][3] += a0 * bv.w;
        acc[1][0] += a1 * bv.x; acc[1][1] += a1 * bv.y; acc[1][2] += a1 * bv.z; acc[1][3] += a1 * bv.w;
        acc[2][0] += a2 * bv.x; acc[2][1] += a2 * bv.y; acc[2][2] += a2 * bv.z; acc[2][3] += a2 * bv.w;
        acc[3][0] += a3 * bv.x; acc[3][1] += a3 * bv.y; acc[3][2] += a3 * bv.z; acc[3][3] += a3 * bv.w;
    }
    for (int i = 0; i < 4; ++i) {
        int p = p0 + r0 + i;
        for (int j = 0; j < 4; ++j) {
            int n = n0 + c0 + j;
            float v = acc[i][j];
            if (n < DIN) {
                xc[(size_t)p * DIN + n] = v;
            } else {
                float s = v / (1.f + __expf(-v));
                zb[(size_t)p * DIN + (n - DIN)] = s;
            }
        }
    }
}

// ---------------------------------------------------------------------------
// K2: depthwise 3x3 conv + bias + silu, register-sliding window along w.
// Block = (w-segment of 8, h, b), 192 threads (one per channel).
// 3 loads/pixel (vs 9) via 6-tap reuse; 2304 blocks (vs 18432).
// ---------------------------------------------------------------------------
__global__ __launch_bounds__(192) void k_conv(const float* __restrict__ xc,
                                              const float* __restrict__ cw,
                                              const float* __restrict__ cb,
                                              float* __restrict__ xs0,
                                              float* __restrict__ xs1) {
    const int d = threadIdx.x;
    const int seg = blockIdx.x;      // 0..5
    const int h = blockIdx.y;        // 0..47
    const int b = blockIdx.z;        // 0..7
    const int w0 = seg * 8;

    const float k00 = cw[d * 9 + 0], k01 = cw[d * 9 + 1], k02 = cw[d * 9 + 2];
    const float k10 = cw[d * 9 + 3], k11 = cw[d * 9 + 4], k12 = cw[d * 9 + 5];
    const float k20 = cw[d * 9 + 6], k21 = cw[d * 9 + 7], k22 = cw[d * 9 + 8];
    const float bias = cb[d];

    #define LDXC(hy, wx) ((((unsigned)(hy) < HD) && ((unsigned)(wx) < WD)) \
        ? xc[((size_t)(b * HD + (hy)) * WD + (wx)) * DIN + d] : 0.f)

    float a0 = LDXC(h - 1, w0 - 1), a1 = LDXC(h, w0 - 1), a2 = LDXC(h + 1, w0 - 1);
    float b0 = LDXC(h - 1, w0),     b1 = LDXC(h, w0),     b2 = LDXC(h + 1, w0);

    for (int i = 0; i < 8; ++i) {
        const int w = w0 + i;
        float c0 = LDXC(h - 1, w + 1), c1 = LDXC(h, w + 1), c2 = LDXC(h + 1, w + 1);
        float acc = bias
                  + a0 * k00 + b0 * k01 + c0 * k02
                  + a1 * k10 + b1 * k11 + c1 * k12
                  + a2 * k20 + b2 * k21 + c2 * k22;
        float v = acc / (1.f + __expf(-acc));
        xs0[((size_t)b * LL + h * WD + w) * DIN + d] = v;
        xs1[((size_t)b * LL + w * HD + h) * DIN + d] = v;
        a0 = b0; a1 = b1; a2 = b2;
        b0 = c0; b1 = c1; b2 = c2;
    }
    #undef LDXC
}

// ---------------------------------------------------------------------------
// K3: x_proj as register-blocked tile GEMM (64 pos x 40 ch per block).
// [R8 measured-good version]
// ---------------------------------------------------------------------------
__global__ __launch_bounds__(256) void k_xproj(const float* __restrict__ xs0,
                                               const float* __restrict__ xs1,
                                               const float* __restrict__ wxp,
                                               float* __restrict__ dtr,
                                               float* __restrict__ Bt,
                                               float* __restrict__ Ct) {
    __shared__ float sxs[64 * 196];
    __shared__ float sw[40 * 192];
    const int k = blockIdx.y;
    const int b = blockIdx.z;
    const int tid = threadIdx.x;
    const int t0 = blockIdx.x * 64;
    const float* src = (k & 1) ? xs1 : xs0;

    for (int i = tid; i < 40 * 48; i += 256) {
        int row = i / 48, j = i % 48;
        float4 v = (row < 38)
            ? ((const float4*)&wxp[((size_t)k * 38 + row) * 192])[j]
            : make_float4(0.f, 0.f, 0.f, 0.f);
        ((float4*)&sw[row * 192])[j] = v;
    }
    for (int i = tid; i < 64 * 48; i += 256) {
        int r = i / 48, j = i % 48;
        int t = t0 + r;
        int ts = (k < 2) ? t : (LL - 1 - t);
        ((float4*)&sxs[r * 196])[j] =
            ((const float4*)&src[((size_t)b * LL + ts) * DIN])[j];
    }
    __syncthreads();

    const int lp = tid & 31;
    const int c0 = (tid >> 5) * 5;
    float acc[2][5] = {};
    const float* x0 = &sxs[lp * 196];
    const float* x1 = &sxs[(lp + 32) * 196];
    for (int d = 0; d < 192; d += 4) {
        float4 a0 = *(const float4*)&x0[d];
        float4 a1 = *(const float4*)&x1[d];
        #pragma unroll
        for (int j = 0; j < 5; ++j) {
            float4 wv = *(const float4*)&sw[(c0 + j) * 192 + d];
            acc[0][j] += a0.x * wv.x + a0.y * wv.y + a0.z * wv.z + a0.w * wv.w;
            acc[1][j] += a1.x * wv.x + a1.y * wv.y + a1.z * wv.z + a1.w * wv.w;
        }
    }

    #pragma unroll
    for (int pp = 0; pp < 2; ++pp) {
        size_t base = (size_t)(b * KK + k) * LL + (t0 + lp + pp * 32);
        #pragma unroll
        for (int j = 0; j < 5; ++j) {
            int c = c0 + j;
            float v = acc[pp][j];
            if (c < RR)               dtr[base * RR + c] = v;
            else if (c < RR + NN)     Bt[base * NN + (c - RR)] = v;
            else if (c < RR + 2 * NN) Ct[base * NN + (c - RR - NN)] = v;
        }
    }
}

// ---------------------------------------------------------------------------
// K4a: chunk-local scan (h0=0) -> hend (chunk final state) + ssp (sum of sp)
// ---------------------------------------------------------------------------
__global__ __launch_bounds__(192) void k_scan1(const float* __restrict__ xs0,
                                               const float* __restrict__ xs1,
                                               const float* __restrict__ dtr,
                                               const float* __restrict__ Bt,
                                               const float* __restrict__ A_logs,
                                               const float* __restrict__ dtw,
                                               const float* __restrict__ dtb,
                                               float* __restrict__ hend,
                                               float* __restrict__ ssp) {
    __shared__ __align__(16) float sB[CH * NN];
    __shared__ __align__(16) float sdt[CH * RR];
    const int c = blockIdx.x, k = blockIdx.y, b = blockIdx.z;
    const int d = threadIdx.x;
    const int kd = k * DIN + d;
    const size_t baseBK = (size_t)(b * KK + k) * LL;
    const int t0 = c * CH;

    for (int i = threadIdx.x; i < CH * NN; i += 192) sB[i] = Bt[(baseBK + t0) * NN + i];
    for (int i = threadIdx.x; i < CH * RR; i += 192) sdt[i] = dtr[(baseBK + t0) * RR + i];
    __syncthreads();

    float a2_[NN];
    #pragma unroll
    for (int n = 0; n < NN; ++n) a2_[n] = -__expf(A_logs[(size_t)kd * NN + n]) * LOG2E;
    float w_[RR];
    #pragma unroll
    for (int r = 0; r < RR; ++r) w_[r] = dtw[(size_t)kd * RR + r];
    const float bias = dtb[kd];
    float h[NN];
    #pragma unroll
    for (int n = 0; n < NN; ++n) h[n] = 0.f;
    float sum_sp = 0.f;

    const float* u_src = (k & 1) ? xs1 : xs0;
    float u_next = u_src[((size_t)b * LL + ((k < 2) ? t0 : (LL - 1 - t0))) * DIN + d];

    for (int tt = 0; tt < CH; ++tt) {
        float u = u_next;
        if (tt + 1 < CH) {
            int tn = t0 + tt + 1;
            int ts = (k < 2) ? tn : (LL - 1 - tn);
            u_next = u_src[((size_t)b * LL + ts) * DIN + d];
        }
        const float2* dr = (const float2*)&sdt[tt * RR];
        float2 d0 = dr[0], d1 = dr[1], d2 = dr[2];
        float xv = bias + d0.x * w_[0] + d0.y * w_[1] + d1.x * w_[2]
                        + d1.y * w_[3] + d2.x * w_[4] + d2.y * w_[5];
        float sp = (xv > 15.f) ? xv
                 : __builtin_amdgcn_logf(1.f + __builtin_amdgcn_exp2f(xv * LOG2E)) * LN2;
        sum_sp += sp;
        float du = sp * u;
        const float4* Bp = (const float4*)&sB[tt * NN];
        #pragma unroll
        for (int q = 0; q < 4; ++q) {
            float4 Bv = Bp[q];
            h[4*q+0] = __builtin_amdgcn_exp2f(sp * a2_[4*q+0]) * h[4*q+0] + du * Bv.x;
            h[4*q+1] = __builtin_amdgcn_exp2f(sp * a2_[4*q+1]) * h[4*q+1] + du * Bv.y;
            h[4*q+2] = __builtin_amdgcn_exp2f(sp * a2_[4*q+2]) * h[4*q+2] + du * Bv.z;
            h[4*q+3] = __builtin_amdgcn_exp2f(sp * a2_[4*q+3]) * h[4*q+3] + du * Bv.w;
        }
    }

    size_t ob = (((size_t)(b * KK + k) * NC + c) * DIN + d) * NN;
    #pragma unroll
    for (int q = 0; q < 4; ++q) {
        *(float4*)&hend[ob + 4 * q] = make_float4(h[4*q], h[4*q+1], h[4*q+2], h[4*q+3]);
    }
    ssp[((size_t)c * (BB * KK) + (b * KK + k)) * DIN + d] = sum_sp;
}

// ---------------------------------------------------------------------------
// K4b: combine chunk states (in place: hend[c] <- h_start for chunk c)
// ---------------------------------------------------------------------------
__global__ __launch_bounds__(256) void k_comb(float* __restrict__ hend,
                                              const float* __restrict__ ssp,
                                              const float* __restrict__ A_logs) {
    const int gid = blockIdx.x * 256 + threadIdx.x;   // ((bk*DIN)+d)*16 + n
    const int n = gid & 15;
    const int dkb = gid >> 4;
    const int d = dkb % DIN;
    const int bk = dkb / DIN;
    const int k = bk & 3;
    const float a2 = -__expf(A_logs[(size_t)(k * DIN + d) * NN + n]) * LOG2E;
    float h = 0.f;
    for (int c = 0; c < NC; ++c) {
        size_t idx = (((size_t)bk * NC + c) * DIN + d) * NN + n;
        float e = hend[idx];
        hend[idx] = h;
        float P = __builtin_amdgcn_exp2f(a2 * ssp[((size_t)c * (BB * KK) + bk) * DIN + d]);
        h = P * h + e;
    }
}

// ---------------------------------------------------------------------------
// K4c: chunk scan with true h0 (from hend) -> y, merged via atomicAdd
// ---------------------------------------------------------------------------
__global__ __launch_bounds__(192) void k_scan2(const float* __restrict__ xs0,
                                               const float* __restrict__ xs1,
                                               const float* __restrict__ dtr,
                                               const float* __restrict__ Bt,
                                               const float* __restrict__ Ct,
                                               const float* __restrict__ A_logs,
                                               const float* __restrict__ Ds,
                                               const float* __restrict__ dtw,
                                               const float* __restrict__ dtb,
                                               const float* __restrict__ hstart,
                                               float* __restrict__ yacc) {
    __shared__ __align__(16) float sB[CH * NN];
    __shared__ __align__(16) float sC[CH * NN];
    __shared__ __align__(16) float sdt[CH * RR];
    const int c = blockIdx.x, k = blockIdx.y, b = blockIdx.z;
    const int d = threadIdx.x;
    const int kd = k * DIN + d;
    const size_t baseBK = (size_t)(b * KK + k) * LL;
    const int t0 = c * CH;

    for (int i = threadIdx.x; i < CH * NN; i += 192) {
        sB[i] = Bt[(baseBK + t0) * NN + i];
        sC[i] = Ct[(baseBK + t0) * NN + i];
    }
    for (int i = threadIdx.x; i < CH * RR; i += 192) sdt[i] = dtr[(baseBK + t0) * RR + i];
    __syncthreads();

    float a2_[NN];
    #pragma unroll
    for (int n = 0; n < NN; ++n) a2_[n] = -__expf(A_logs[(size_t)kd * NN + n]) * LOG2E;
    float w_[RR];
    #pragma unroll
    for (int r = 0; r < RR; ++r) w_[r] = dtw[(size_t)kd * RR + r];
    const float bias = dtb[kd];
    const float Dv = Ds[kd];

    float h[NN];
    size_t hb = (((size_t)(b * KK + k) * NC + c) * DIN + d) * NN;
    #pragma unroll
    for (int q = 0; q < 4; ++q) {
        float4 hv = *(const float4*)&hstart[hb + 4 * q];
        h[4*q] = hv.x; h[4*q+1] = hv.y; h[4*q+2] = hv.z; h[4*q+3] = hv.w;
    }

    const float* u_src = (k & 1) ? xs1 : xs0;
    float u_next = u_src[((size_t)b * LL + ((k < 2) ? t0 : (LL - 1 - t0))) * DIN + d];

    for (int tt = 0; tt < CH; ++tt) {
        float u = u_next;
        if (tt + 1 < CH) {
            int tn = t0 + tt + 1;
            int ts = (k < 2) ? tn : (LL - 1 - tn);
            u_next = u_src[((size_t)b * LL + ts) * DIN + d];
        }
        const float2* dr = (const float2*)&sdt[tt * RR];
        float2 d0 = dr[0], d1 = dr[1], d2 = dr[2];
        float xv = bias + d0.x * w_[0] + d0.y * w_[1] + d1.x * w_[2]
                        + d1.y * w_[3] + d2.x * w_[4] + d2.y * w_[5];
        float sp = (xv > 15.f) ? xv
                 : __builtin_amdgcn_logf(1.f + __builtin_amdgcn_exp2f(xv * LOG2E)) * LN2;
        float du = sp * u;
        const float4* Bp = (const float4*)&sB[tt * NN];
        const float4* Cp = (const float4*)&sC[tt * NN];
        float y = 0.f;
        #pragma unroll
        for (int q = 0; q < 4; ++q) {
            float4 Bv = Bp[q], Cv = Cp[q];
            h[4*q+0] = __builtin_amdgcn_exp2f(sp * a2_[4*q+0]) * h[4*q+0] + du * Bv.x; y += h[4*q+0] * Cv.x;
            h[4*q+1] = __builtin_amdgcn_exp2f(sp * a2_[4*q+1]) * h[4*q+1] + du * Bv.y; y += h[4*q+1] * Cv.y;
            h[4*q+2] = __builtin_amdgcn_exp2f(sp * a2_[4*q+2]) * h[4*q+2] + du * Bv.z; y += h[4*q+2] * Cv.z;
            h[4*q+3] = __builtin_amdgcn_exp2f(sp * a2_[4*q+3]) * h[4*q+3] + du * Bv.w; y += h[4*q+3] * Cv.w;
        }
        y += Dv * u;

        int t = t0 + tt;
        int pos;
        if (k == 0)      pos = t;
        else if (k == 2) pos = LL - 1 - t;
        else if (k == 1) pos = (t % HD) * WD + (t / HD);
        else { int tr = LL - 1 - t; pos = (tr % HD) * WD + (tr / HD); }

        atomicAdd(&yacc[((size_t)b * LL + pos) * DIN + d], y);
    }
}

// ---------------------------------------------------------------------------
// K5: fused LayerNorm + gate + out_proj as LDS-tiled GEMM (reads merged yacc).
// ---------------------------------------------------------------------------
__global__ __launch_bounds__(256) void k_final(const float* __restrict__ yacc,
                                               const float* __restrict__ zb,
                                               const float* __restrict__ g,
                                               const float* __restrict__ bta,
                                               const float* __restrict__ wo,
                                               float* __restrict__ out) {
    __shared__ float syn[32 * 194];
    __shared__ float swo[96 * 98];
    const int tid = threadIdx.x;
    const int P0 = blockIdx.x * 32;

    {
        const int p = tid >> 3;
        const int q = tid & 7;
        const float* yr = &yacc[((size_t)(P0 + p)) * DIN + q * 24];
        float4 v0 = ((const float4*)yr)[0];
        float4 v1 = ((const float4*)yr)[1];
        float4 v2 = ((const float4*)yr)[2];
        float4 v3 = ((const float4*)yr)[3];
        float4 v4 = ((const float4*)yr)[4];
        float4 v5 = ((const float4*)yr)[5];
        float s  = v0.x+v0.y+v0.z+v0.w + v1.x+v1.y+v1.z+v1.w + v2.x+v2.y+v2.z+v2.w
                 + v3.x+v3.y+v3.z+v3.w + v4.x+v4.y+v4.z+v4.w + v5.x+v5.y+v5.z+v5.w;
        float sq = v0.x*v0.x+v0.y*v0.y+v0.z*v0.z+v0.w*v0.w
                 + v1.x*v1.x+v1.y*v1.y+v1.z*v1.z+v1.w*v1.w
                 + v2.x*v2.x+v2.y*v2.y+v2.z*v2.z+v2.w*v2.w
                 + v3.x*v3.x+v3.y*v3.y+v3.z*v3.z+v3.w*v3.w
                 + v4.x*v4.x+v4.y*v4.y+v4.z*v4.z+v4.w*v4.w
                 + v5.x*v5.x+v5.y*v5.y+v5.z*v5.z+v5.w*v5.w;
        #pragma unroll
        for (int off = 1; off < 8; off <<= 1) {
            s  += __shfl_xor(s, off);
            sq += __shfl_xor(sq, off);
        }
        float mu = s * (1.f / DIN);
        float rs = rsqrtf(sq * (1.f / DIN) - mu * mu + 1e-5f);

        const float* zr = &zb[((size_t)(P0 + p)) * DIN + q * 24];
        const float* gr = &g[q * 24];
        const float* br = &bta[q * 24];
        float* sy = &syn[p * 194 + q * 24];
        #pragma unroll
        for (int j = 0; j < 6; ++j) {
            float4 vv = (j == 0) ? v0 : (j == 1) ? v1 : (j == 2) ? v2
                      : (j == 3) ? v3 : (j == 4) ? v4 : v5;
            float4 gv = ((const float4*)gr)[j];
            float4 bv = ((const float4*)br)[j];
            float4 zv = ((const float4*)zr)[j];
            float t0 = ((vv.x - mu) * rs * gv.x + bv.x) * zv.x;
            float t1 = ((vv.y - mu) * rs * gv.y + bv.y) * zv.y;
            float t2 = ((vv.z - mu) * rs * gv.z + bv.z) * zv.z;
            float t3 = ((vv.w - mu) * rs * gv.w + bv.w) * zv.w;
            ((float2*)sy)[2 * j]     = make_float2(t0, t1);
            ((float2*)sy)[2 * j + 1] = make_float2(t2, t3);
        }
    }

    const int tx = tid & 15;
    const int ty = tid >> 4;
    const int c0 = tx * 6;
    const int p0 = ty * 2;
    float acc[2][6] = {};

    for (int kb = 0; kb < 2; ++kb) {
        __syncthreads();
        for (int i = tid; i < 96 * 96; i += 256) {
            int n = i / 96, k = i - n * 96;
            swo[k * 98 + n] = wo[(size_t)n * DIN + kb * 96 + k];
        }
        __syncthreads();
        const float* sy0 = &syn[p0 * 194 + kb * 96];
        const float* sy1 = &syn[(p0 + 1) * 194 + kb * 96];
        #pragma unroll 4
        for (int k = 0; k < 96; ++k) {
            float a0 = sy0[k];
            float a1 = sy1[k];
            const float2* wp = (const float2*)&swo[k * 98 + c0];
            float2 w01 = wp[0], w23 = wp[1], w45 = wp[2];
            acc[0][0] += a0 * w01.x; acc[0][1] += a0 * w01.y;
            acc[0][2] += a0 * w23.x; acc[0][3] += a0 * w23.y;
            acc[0][4] += a0 * w45.x; acc[0][5] += a0 * w45.y;
            acc[1][0] += a1 * w01.x; acc[1][1] += a1 * w01.y;
            acc[1][2] += a1 * w23.x; acc[1][3] += a1 * w23.y;
            acc[1][4] += a1 * w45.x; acc[1][5] += a1 * w45.y;
        }
    }

    #pragma unroll
    for (int i = 0; i < 2; ++i) {
        float* orow = &out[((size_t)(P0 + p0 + i)) * DM + c0];
        orow[0] = acc[i][0]; orow[1] = acc[i][1]; orow[2] = acc[i][2];
        orow[3] = acc[i][3]; orow[4] = acc[i][4]; orow[5] = acc[i][5];
    }
}

// ---------------------------------------------------------------------------
extern "C" void kernel_launch(void* const* d_in, const int* in_sizes, int n_in,
                              void* d_out, int out_size, void* d_ws, size_t ws_size,
                              hipStream_t stream) {
    const float* x      = (const float*)d_in[0];
    const float* w_in   = (const float*)d_in[1];
    const float* conv_w = (const float*)d_in[2];
    const float* conv_b = (const float*)d_in[3];
    const float* w_xp   = (const float*)d_in[4];
    const float* dtw    = (const float*)d_in[5];
    const float* dtb    = (const float*)d_in[6];
    const float* A_logs = (const float*)d_in[7];
    const float* Ds     = (const float*)d_in[8];
    const float* ln_g   = (const float*)d_in[9];
    const float* ln_b   = (const float*)d_in[10];
    const float* w_out  = (const float*)d_in[11];
    float* out = (float*)d_out;

    float* ws = (float*)d_ws;
    size_t o = 0;
    float* xc  = ws + o; o += (size_t)BB * LL * DIN;
    float* zb  = ws + o; o += (size_t)BB * LL * DIN;
    float* xs0 = ws + o; o += (size_t)BB * LL * DIN;
    float* xs1 = ws + o; o += (size_t)BB * LL * DIN;
    float* Btb = ws + o; o += (size_t)BB * KK * LL * NN;
    float* Ctb = ws + o; o += (size_t)BB * KK * LL * NN;
    float* dtrb= ws + o; o += (size_t)BB * KK * LL * RR;
    float* yac = ws + o; o += (size_t)BB * LL * DIN;
    float* hend= ws + o; o += (size_t)BB * KK * NC * DIN * NN;
    float* ssp = ws + o; o += (size_t)NC * BB * KK * DIN;

    hipMemsetAsync(yac, 0, sizeof(float) * (size_t)BB * LL * DIN, stream);

    dim3 g1(288, 6);
    k_inproj<<<g1, 256, 0, stream>>>(x, w_in, xc, zb);

    dim3 g2(WD / 8, HD, BB);
    k_conv<<<g2, DIN, 0, stream>>>(xc, conv_w, conv_b, xs0, xs1);

    dim3 g3(LL / 64, KK, BB);
    k_xproj<<<g3, 256, 0, stream>>>(xs0, xs1, w_xp, dtrb, Btb, Ctb);

    dim3 gs(NC, KK, BB);
    k_scan1<<<gs, DIN, 0, stream>>>(xs0, xs1, dtrb, Btb, A_logs, dtw, dtb, hend, ssp);
    k_comb<<<(BB * KK * DIN * NN) / 256, 256, 0, stream>>>(hend, ssp, A_logs);
    k_scan2<<<gs, DIN, 0, stream>>>(xs0, xs1, dtrb, Btb, Ctb, A_logs, Ds, dtw, dtb,
                                    hend, yac);

    k_final<<<BB * LL / 32, 256, 0, stream>>>(yac, zb, ln_g, ln_b, w_out, out);
}